// Round 2
// baseline (178.545 us; speedup 1.0000x reference)
//
#include <hip/hip_runtime.h>
#include <math.h>

// Problem constants (from reference setup_inputs)
#define BATCH   2
#define NBOX    512
#define KTOT    (BATCH * NBOX)   // 1024 ROIs
#define CCH     256
#define OUTHW   7
#define PIX     (OUTHW * OUTHW)  // 49
#define CPT     4                // channels per thread
#define NC4     (CCH / CPT)      // 64
// threads per ROI = NC4*PIX = 3136 = 49 waves exactly -> level branch is wave-uniform

// ---------------- setup: per-ROI params into ws ----------------
// ws layout per k (8 floats): rx1, ry1, bin_w, bin_h, lvl(as int bits), unused...
__global__ __launch_bounds__(256) void roi_setup(
    const float* __restrict__ boxes, float* __restrict__ ws)
{
    const int k = blockIdx.x * blockDim.x + threadIdx.x;
    if (k >= KTOT) return;

    const float bx1 = boxes[4 * k + 0];
    const float by1 = boxes[4 * k + 1];
    const float bx2 = boxes[4 * k + 2];
    const float by2 = boxes[4 * k + 3];

    const float area = fmaxf((bx2 - bx1) * (by2 - by1), 0.0f);
    const float s    = sqrtf(area);
    float lvlf = floorf(4.0f + log2f(s / 224.0f) + 1e-6f);
    lvlf = fminf(fmaxf(lvlf, 2.0f), 5.0f);   // clip before cast (handles -inf)
    const int lvl = (int)lvlf - 2;           // 0..3

    // scale = 2^-(lvl+2)
    const float scale = 0.25f * exp2f(-(float)lvl);

    const float rx1 = bx1 * scale;
    const float ry1 = by1 * scale;
    const float rx2 = bx2 * scale;
    const float ry2 = by2 * scale;
    const float bin_w = fmaxf(rx2 - rx1, 1.0f) / (float)OUTHW;
    const float bin_h = fmaxf(ry2 - ry1, 1.0f) / (float)OUTHW;

    float* o = ws + (size_t)k * 8;
    o[0] = rx1;
    o[1] = ry1;
    o[2] = bin_w;
    o[3] = bin_h;
    o[4] = __int_as_float(lvl);
    o[5] = 0.0f; o[6] = 0.0f; o[7] = 0.0f;
}

// ---------------- main: templated on feature H,W ----------------
template <int H, int W>
__device__ __forceinline__ void roi_compute(
    const float* __restrict__ fbase,   // -> plane (b, c4*CPT)
    float rx1, float ry1, float bw, float bh,
    int ph, int pw,
    float* __restrict__ outp)          // -> out[k, c4*CPT, ph, pw]
{
    float wgt[16];
    int   off[4];

    #pragma unroll
    for (int sy = 0; sy < 2; ++sy) {
        const float y  = ry1 + (float)ph * bh + ((float)sy + 0.5f) * bh / 2.0f;
        const bool  vy = (y >= -1.0f) && (y <= (float)H);
        const float yc = fminf(fmaxf(y, 0.0f), (float)(H - 1));
        int yl = (int)yc;                 // yc >= 0, trunc == floor
        if (yl > H - 2) yl = H - 2;
        const float ly = yc - (float)yl;

        #pragma unroll
        for (int sx = 0; sx < 2; ++sx) {
            const float x  = rx1 + (float)pw * bw + ((float)sx + 0.5f) * bw / 2.0f;
            const bool  vx = (x >= -1.0f) && (x <= (float)W);
            const float xc = fminf(fmaxf(x, 0.0f), (float)(W - 1));
            int xl = (int)xc;
            if (xl > W - 2) xl = W - 2;
            const float lx = xc - (float)xl;

            const float v = (vy && vx) ? 1.0f : 0.0f;
            const int si = sy * 2 + sx;
            wgt[si * 4 + 0] = (1.0f - ly) * (1.0f - lx) * v;
            wgt[si * 4 + 1] = (1.0f - ly) * lx * v;
            wgt[si * 4 + 2] = ly * (1.0f - lx) * v;
            wgt[si * 4 + 3] = ly * lx * v;
            off[si] = yl * W + xl;
        }
    }

    float acc[CPT] = {0.0f, 0.0f, 0.0f, 0.0f};
    #pragma unroll
    for (int si = 0; si < 4; ++si) {
        #pragma unroll
        for (int c = 0; c < CPT; ++c) {
            const float* pp = fbase + c * (H * W) + off[si];
            // pp[1], pp[W], pp[W+1] fold into load immediate offsets (<= 804B)
            acc[c] = fmaf(wgt[si * 4 + 0], pp[0],
                     fmaf(wgt[si * 4 + 1], pp[1],
                     fmaf(wgt[si * 4 + 2], pp[W],
                     fmaf(wgt[si * 4 + 3], pp[W + 1], acc[c]))));
        }
    }

    #pragma unroll
    for (int c = 0; c < CPT; ++c) {
        __builtin_nontemporal_store(acc[c] * 0.25f, outp + c * PIX);
    }
}

__global__ __launch_bounds__(256) void msroi_main(
    const float* __restrict__ f0,   // [2,256,200,200]
    const float* __restrict__ f1,   // [2,256,100,100]
    const float* __restrict__ f2,   // [2,256, 50, 50]
    const float* __restrict__ f3,   // [2,256, 25, 25]
    const float* __restrict__ ws,
    float* __restrict__ out)        // [K,256,7,7]
{
    const int t = blockIdx.x * blockDim.x + threadIdx.x;
    const int total = KTOT * NC4 * PIX;   // 3,211,264 (exact multiple of 256)
    if (t >= total) return;

    const int k   = t / (NC4 * PIX);
    const int rem = t % (NC4 * PIX);
    const int c4  = rem / PIX;
    const int p   = rem % PIX;
    const int ph  = p / OUTHW;
    const int pw  = p % OUTHW;

    const float* prm = ws + (size_t)k * 8;
    const float rx1 = prm[0];
    const float ry1 = prm[1];
    const float bw  = prm[2];
    const float bh  = prm[3];
    const int   lvl = __float_as_int(prm[4]);

    const int b = k >> 9;               // k / NBOX
    const int cbase = b * CCH + c4 * CPT;

    float* outp = out + ((size_t)k * CCH + c4 * CPT) * PIX + p;

    switch (lvl) {  // wave-uniform: each ROI owns exactly 49 full waves
        case 0:
            roi_compute<200, 200>(f0 + (size_t)cbase * (200 * 200), rx1, ry1, bw, bh, ph, pw, outp);
            break;
        case 1:
            roi_compute<100, 100>(f1 + (size_t)cbase * (100 * 100), rx1, ry1, bw, bh, ph, pw, outp);
            break;
        case 2:
            roi_compute<50, 50>(f2 + (size_t)cbase * (50 * 50), rx1, ry1, bw, bh, ph, pw, outp);
            break;
        default:
            roi_compute<25, 25>(f3 + (size_t)cbase * (25 * 25), rx1, ry1, bw, bh, ph, pw, outp);
            break;
    }
}

extern "C" void kernel_launch(void* const* d_in, const int* in_sizes, int n_in,
                              void* d_out, int out_size, void* d_ws, size_t ws_size,
                              hipStream_t stream) {
    const float* f0    = (const float*)d_in[0];
    const float* f1    = (const float*)d_in[1];
    const float* f2    = (const float*)d_in[2];
    const float* f3    = (const float*)d_in[3];
    const float* boxes = (const float*)d_in[4];
    float* out = (float*)d_out;
    float* ws  = (float*)d_ws;          // needs 1024*8*4 = 32 KB

    roi_setup<<<(KTOT + 255) / 256, 256, 0, stream>>>(boxes, ws);

    const int total = KTOT * NC4 * PIX;
    msroi_main<<<(total + 255) / 256, 256, 0, stream>>>(f0, f1, f2, f3, ws, out);
}

// Round 3
// 142.229 us; speedup vs baseline: 1.2553x; 1.2553x over previous
//
#include <hip/hip_runtime.h>
#include <math.h>

// Problem constants (from reference setup_inputs)
#define BATCH   2
#define NBOX    512
#define KTOT    (BATCH * NBOX)   // 1024 ROIs
#define CCH     256
#define OUTHW   7
#define PIX     (OUTHW * OUTHW)  // 49

// ===================== fallback (round-1 kernel, no ws needed) =====================
__global__ __launch_bounds__(256) void msroi_fallback(
    const float* __restrict__ f0, const float* __restrict__ f1,
    const float* __restrict__ f2, const float* __restrict__ f3,
    const float* __restrict__ boxes, float* __restrict__ out)
{
    const int t = blockIdx.x * blockDim.x + threadIdx.x;
    const int total = KTOT * CCH * PIX;
    if (t >= total) return;

    const int p  = t % PIX;
    const int c  = (t / PIX) % CCH;
    const int k  = t / (PIX * CCH);
    const int ph = p / OUTHW;
    const int pw = p % OUTHW;

    const float bx1 = boxes[k * 4 + 0];
    const float by1 = boxes[k * 4 + 1];
    const float bx2 = boxes[k * 4 + 2];
    const float by2 = boxes[k * 4 + 3];

    const float area = fmaxf((bx2 - bx1) * (by2 - by1), 0.0f);
    const float s    = sqrtf(area);
    float lvlf = floorf(4.0f + log2f(s / 224.0f) + 1e-6f);
    lvlf = fminf(fmaxf(lvlf, 2.0f), 5.0f);
    const int lvl = (int)lvlf - 2;

    const float* feat; int H, W; float scale;
    switch (lvl) {
        case 0:  feat = f0; H = 200; W = 200; scale = 0.25f;    break;
        case 1:  feat = f1; H = 100; W = 100; scale = 0.125f;   break;
        case 2:  feat = f2; H =  50; W =  50; scale = 0.0625f;  break;
        default: feat = f3; H =  25; W =  25; scale = 0.03125f; break;
    }

    const int b = k / NBOX;
    const float* __restrict__ fc = feat + ((size_t)(b * CCH + c)) * (size_t)(H * W);

    const float rx1 = bx1 * scale, ry1 = by1 * scale;
    const float rx2 = bx2 * scale, ry2 = by2 * scale;
    const float bin_w = fmaxf(rx2 - rx1, 1.0f) / (float)OUTHW;
    const float bin_h = fmaxf(ry2 - ry1, 1.0f) / (float)OUTHW;
    const float Hf = (float)H, Wf = (float)W;

    float acc = 0.0f;
    #pragma unroll
    for (int sy = 0; sy < 2; ++sy) {
        const float y  = ry1 + (float)ph * bin_h + ((float)sy + 0.5f) * bin_h / 2.0f;
        const bool  vy = (y >= -1.0f) && (y <= Hf);
        const float yc = fminf(fmaxf(y, 0.0f), Hf - 1.0f);
        int yl = (int)yc; if (yl > H - 2) yl = H - 2;
        const float ly = yc - (float)yl;
        #pragma unroll
        for (int sx = 0; sx < 2; ++sx) {
            const float x  = rx1 + (float)pw * bin_w + ((float)sx + 0.5f) * bin_w / 2.0f;
            const bool  vx = (x >= -1.0f) && (x <= Wf);
            const float xc = fminf(fmaxf(x, 0.0f), Wf - 1.0f);
            int xl = (int)xc; if (xl > W - 2) xl = W - 2;
            const float lx = xc - (float)xl;
            if (vy && vx) {
                const float* p00 = fc + (size_t)yl * W + xl;
                acc += (1.0f - ly) * (1.0f - lx) * p00[0]
                     + (1.0f - ly) * lx          * p00[1]
                     + ly          * (1.0f - lx) * p00[W]
                     + ly          * lx          * p00[W + 1];
            }
        }
    }
    out[t] = acc * 0.25f;
}

// ===================== fast path =====================

// NCHW -> NHWC per level: src [B][256][S] -> dst [B][S][256], S = H*W
__global__ __launch_bounds__(256) void nchw_to_nhwc(
    const float* __restrict__ src, float* __restrict__ dst, int S)
{
    __shared__ float tile[64][65];
    const int tx = (int)(threadIdx.x & 63u);
    const int ty = (int)(threadIdx.x >> 6);
    const int s0 = blockIdx.x * 64;
    const int c0 = blockIdx.y * 64;
    const int b  = blockIdx.z;

    const float* sp = src + ((size_t)b * CCH + c0) * (size_t)S;
    #pragma unroll
    for (int i = 0; i < 16; ++i) {
        const int c = ty * 16 + i;
        const int s = s0 + tx;
        if (s < S) tile[c][tx] = sp[(size_t)c * S + s];
    }
    __syncthreads();
    float* dp = dst + (size_t)b * S * CCH + c0;
    #pragma unroll
    for (int i = 0; i < 16; ++i) {
        const int s = s0 + ty * 16 + i;
        if (s < S) dp[(size_t)s * CCH + tx] = tile[tx][ty * 16 + i];
    }
}

// gather: block = one ROI (4 waves), lane = channel-quad, wave = pixel subset.
// outT layout: [K][49][256]  (NHWC output, fully coalesced float4 stores)
__global__ __launch_bounds__(256) void msroi_gather(
    const float* __restrict__ g0, const float* __restrict__ g1,
    const float* __restrict__ g2, const float* __restrict__ g3,
    const float* __restrict__ boxes, float* __restrict__ outT)
{
    const int k    = blockIdx.x;
    const int lane = (int)(threadIdx.x & 63u);
    const int wave = (int)(threadIdx.x >> 6);

    // per-ROI params (redundant per thread; wave-uniform)
    const float bx1 = boxes[4 * k + 0];
    const float by1 = boxes[4 * k + 1];
    const float bx2 = boxes[4 * k + 2];
    const float by2 = boxes[4 * k + 3];

    const float area = fmaxf((bx2 - bx1) * (by2 - by1), 0.0f);
    const float s    = sqrtf(area);
    float lvlf = floorf(4.0f + log2f(s / 224.0f) + 1e-6f);
    lvlf = fminf(fmaxf(lvlf, 2.0f), 5.0f);
    const int lvl = (int)lvlf - 2;

    const float* g; int H, W; float scale;
    switch (lvl) {
        case 0:  g = g0; H = 200; W = 200; scale = 0.25f;    break;
        case 1:  g = g1; H = 100; W = 100; scale = 0.125f;   break;
        case 2:  g = g2; H =  50; W =  50; scale = 0.0625f;  break;
        default: g = g3; H =  25; W =  25; scale = 0.03125f; break;
    }

    const int b = k >> 9;   // k / NBOX
    // NHWC batch plane, offset to this lane's channel quad
    const float* __restrict__ fc = g + (size_t)b * (size_t)(H * W) * CCH + 4 * lane;

    const float rx1 = bx1 * scale, ry1 = by1 * scale;
    const float rx2 = bx2 * scale, ry2 = by2 * scale;
    const float bw = fmaxf(rx2 - rx1, 1.0f) / (float)OUTHW;
    const float bh = fmaxf(ry2 - ry1, 1.0f) / (float)OUTHW;
    const float Hf = (float)H, Wf = (float)W;
    const int rowstride = W * CCH;

    float* __restrict__ op = outT + (size_t)k * (PIX * CCH) + 4 * lane;

    for (int i = 0; i < 13; ++i) {
        const int p = wave * 13 + i;
        if (p > 48) break;               // wave-uniform
        const int ph = p / OUTHW;
        const int pw = p % OUTHW;

        float a0 = 0.0f, a1 = 0.0f, a2 = 0.0f, a3 = 0.0f;

        #pragma unroll
        for (int sy = 0; sy < 2; ++sy) {
            const float y  = ry1 + (float)ph * bh + ((float)sy + 0.5f) * bh / 2.0f;
            const bool  vy = (y >= -1.0f) && (y <= Hf);
            const float yc = fminf(fmaxf(y, 0.0f), Hf - 1.0f);
            int yl = (int)yc; if (yl > H - 2) yl = H - 2;
            const float ly = yc - (float)yl;

            #pragma unroll
            for (int sx = 0; sx < 2; ++sx) {
                const float x  = rx1 + (float)pw * bw + ((float)sx + 0.5f) * bw / 2.0f;
                const bool  vx = (x >= -1.0f) && (x <= Wf);
                const float xc = fminf(fmaxf(x, 0.0f), Wf - 1.0f);
                int xl = (int)xc; if (xl > W - 2) xl = W - 2;
                const float lx = xc - (float)xl;

                const float v   = (vy && vx) ? 1.0f : 0.0f;
                const float w00 = (1.0f - ly) * (1.0f - lx) * v;
                const float w01 = (1.0f - ly) * lx * v;
                const float w10 = ly * (1.0f - lx) * v;
                const float w11 = ly * lx * v;

                const float* r0 = fc + ((size_t)yl * W + xl) * CCH;
                const float* r1 = r0 + rowstride;
                const float4 p00 = *reinterpret_cast<const float4*>(r0);
                const float4 p01 = *reinterpret_cast<const float4*>(r0 + CCH);
                const float4 p10 = *reinterpret_cast<const float4*>(r1);
                const float4 p11 = *reinterpret_cast<const float4*>(r1 + CCH);

                a0 = fmaf(w00, p00.x, fmaf(w01, p01.x, fmaf(w10, p10.x, fmaf(w11, p11.x, a0))));
                a1 = fmaf(w00, p00.y, fmaf(w01, p01.y, fmaf(w10, p10.y, fmaf(w11, p11.y, a1))));
                a2 = fmaf(w00, p00.z, fmaf(w01, p01.z, fmaf(w10, p10.z, fmaf(w11, p11.z, a2))));
                a3 = fmaf(w00, p00.w, fmaf(w01, p01.w, fmaf(w10, p10.w, fmaf(w11, p11.w, a3))));
            }
        }

        float4 o;
        o.x = a0 * 0.25f; o.y = a1 * 0.25f; o.z = a2 * 0.25f; o.w = a3 * 0.25f;
        *reinterpret_cast<float4*>(op + p * CCH) = o;
    }
}

// outT [K][49][256] -> out [K][256][49]
__global__ __launch_bounds__(256) void out_transpose(
    const float* __restrict__ in, float* __restrict__ out)
{
    __shared__ float tile[PIX][65];
    const int k  = blockIdx.x;
    const int cg = blockIdx.y;           // channel group of 64
    const int tx = (int)(threadIdx.x & 63u);
    const int ty = (int)(threadIdx.x >> 6);

    const float* ip = in + (size_t)k * (PIX * CCH) + cg * 64;
    #pragma unroll
    for (int i = 0; i < 13; ++i) {
        const int p = ty * 13 + i;
        if (p < PIX) tile[p][tx] = ip[p * CCH + tx];
    }
    __syncthreads();

    float* op = out + (size_t)k * (PIX * CCH) + (size_t)cg * 64 * PIX;
    #pragma unroll
    for (int j = 0; j < 13; ++j) {
        const int flat = j * 256 + (int)threadIdx.x;   // c_local*49 + p, < 3136
        if (flat < 64 * PIX) {
            const int cl = flat / PIX;
            const int p  = flat % PIX;
            op[flat] = tile[p][cl];
        }
    }
}

// ===================== launch =====================
extern "C" void kernel_launch(void* const* d_in, const int* in_sizes, int n_in,
                              void* d_out, int out_size, void* d_ws, size_t ws_size,
                              hipStream_t stream) {
    const float* f0    = (const float*)d_in[0];
    const float* f1    = (const float*)d_in[1];
    const float* f2    = (const float*)d_in[2];
    const float* f3    = (const float*)d_in[3];
    const float* boxes = (const float*)d_in[4];
    float* out = (float*)d_out;
    float* ws  = (float*)d_ws;

    const size_t n0 = 2ull * 200 * 200 * CCH;   // 20,480,000
    const size_t n1 = 2ull * 100 * 100 * CCH;   //  5,120,000
    const size_t n2 = 2ull *  50 *  50 * CCH;   //  1,280,000
    const size_t n3 = 2ull *  25 *  25 * CCH;   //    320,000
    const size_t nT = (size_t)KTOT * PIX * CCH; // 12,845,056
    const size_t need = (n0 + n1 + n2 + n3 + nT) * sizeof(float);  // ~160.2 MB

    if (ws_size >= need) {
        float* g0 = ws;
        float* g1 = g0 + n0;
        float* g2 = g1 + n1;
        float* g3 = g2 + n2;
        float* oT = g3 + n3;

        nchw_to_nhwc<<<dim3(625, 4, 2), 256, 0, stream>>>(f0, g0, 40000);
        nchw_to_nhwc<<<dim3(157, 4, 2), 256, 0, stream>>>(f1, g1, 10000);
        nchw_to_nhwc<<<dim3( 40, 4, 2), 256, 0, stream>>>(f2, g2,  2500);
        nchw_to_nhwc<<<dim3( 10, 4, 2), 256, 0, stream>>>(f3, g3,   625);

        msroi_gather<<<dim3(KTOT), 256, 0, stream>>>(g0, g1, g2, g3, boxes, oT);

        out_transpose<<<dim3(KTOT, 4), 256, 0, stream>>>(oT, out);
    } else {
        const int total = KTOT * CCH * PIX;
        msroi_fallback<<<(total + 255) / 256, 256, 0, stream>>>(f0, f1, f2, f3, boxes, out);
    }
}

// Round 4
// 97.517 us; speedup vs baseline: 1.8309x; 1.4585x over previous
//
#include <hip/hip_runtime.h>
#include <math.h>

// Problem constants (from reference setup_inputs)
#define BATCH   2
#define NBOX    512
#define KTOT    (BATCH * NBOX)   // 1024 ROIs
#define CCH     256
#define OUTHW   7
#define PIX     (OUTHW * OUTHW)  // 49
#define LDS_STRIDE 261           // odd stride -> conflict-light LDS transpose

typedef unsigned int u32;
typedef unsigned short u16;

__device__ __forceinline__ u16 f32_to_bf16(float f) {
    u32 u = __float_as_uint(f);
    u32 r = (u + 0x7fffu + ((u >> 16) & 1u)) >> 16;   // RNE
    return (u16)r;
}

// ===================== fallback (round-1 kernel, no ws needed) =====================
__global__ __launch_bounds__(256) void msroi_fallback(
    const float* __restrict__ f0, const float* __restrict__ f1,
    const float* __restrict__ f2, const float* __restrict__ f3,
    const float* __restrict__ boxes, float* __restrict__ out)
{
    const int t = blockIdx.x * blockDim.x + threadIdx.x;
    const int total = KTOT * CCH * PIX;
    if (t >= total) return;

    const int p  = t % PIX;
    const int c  = (t / PIX) % CCH;
    const int k  = t / (PIX * CCH);
    const int ph = p / OUTHW;
    const int pw = p % OUTHW;

    const float bx1 = boxes[k * 4 + 0];
    const float by1 = boxes[k * 4 + 1];
    const float bx2 = boxes[k * 4 + 2];
    const float by2 = boxes[k * 4 + 3];

    const float area = fmaxf((bx2 - bx1) * (by2 - by1), 0.0f);
    const float s    = sqrtf(area);
    float lvlf = floorf(4.0f + log2f(s / 224.0f) + 1e-6f);
    lvlf = fminf(fmaxf(lvlf, 2.0f), 5.0f);
    const int lvl = (int)lvlf - 2;

    const float* feat; int H, W; float scale;
    switch (lvl) {
        case 0:  feat = f0; H = 200; W = 200; scale = 0.25f;    break;
        case 1:  feat = f1; H = 100; W = 100; scale = 0.125f;   break;
        case 2:  feat = f2; H =  50; W =  50; scale = 0.0625f;  break;
        default: feat = f3; H =  25; W =  25; scale = 0.03125f; break;
    }

    const int b = k / NBOX;
    const float* __restrict__ fc = feat + ((size_t)(b * CCH + c)) * (size_t)(H * W);

    const float rx1 = bx1 * scale, ry1 = by1 * scale;
    const float rx2 = bx2 * scale, ry2 = by2 * scale;
    const float bin_w = fmaxf(rx2 - rx1, 1.0f) / (float)OUTHW;
    const float bin_h = fmaxf(ry2 - ry1, 1.0f) / (float)OUTHW;
    const float Hf = (float)H, Wf = (float)W;

    float acc = 0.0f;
    #pragma unroll
    for (int sy = 0; sy < 2; ++sy) {
        const float y  = ry1 + (float)ph * bin_h + ((float)sy + 0.5f) * bin_h / 2.0f;
        const bool  vy = (y >= -1.0f) && (y <= Hf);
        const float yc = fminf(fmaxf(y, 0.0f), Hf - 1.0f);
        int yl = (int)yc; if (yl > H - 2) yl = H - 2;
        const float ly = yc - (float)yl;
        #pragma unroll
        for (int sx = 0; sx < 2; ++sx) {
            const float x  = rx1 + (float)pw * bin_w + ((float)sx + 0.5f) * bin_w / 2.0f;
            const bool  vx = (x >= -1.0f) && (x <= Wf);
            const float xc = fminf(fmaxf(x, 0.0f), Wf - 1.0f);
            int xl = (int)xc; if (xl > W - 2) xl = W - 2;
            const float lx = xc - (float)xl;
            if (vy && vx) {
                const float* p00 = fc + (size_t)yl * W + xl;
                acc += (1.0f - ly) * (1.0f - lx) * p00[0]
                     + (1.0f - ly) * lx          * p00[1]
                     + ly          * (1.0f - lx) * p00[W]
                     + ly          * lx          * p00[W + 1];
            }
        }
    }
    out[t] = acc * 0.25f;
}

// ===================== fast path =====================

// NCHW fp32 -> NHWC bf16: src [B][256][S] -> dst [B][S][256]
__global__ __launch_bounds__(256) void nchw_to_nhwc_bf16(
    const float* __restrict__ src, u16* __restrict__ dst, int S)
{
    __shared__ float tile[64][65];
    const int tx = (int)(threadIdx.x & 63u);
    const int ty = (int)(threadIdx.x >> 6);
    const int s0 = blockIdx.x * 64;
    const int c0 = blockIdx.y * 64;
    const int b  = blockIdx.z;

    const float* sp = src + ((size_t)b * CCH + c0) * (size_t)S;
    #pragma unroll
    for (int i = 0; i < 16; ++i) {
        const int c = ty * 16 + i;
        const int s = s0 + tx;
        if (s < S) tile[c][tx] = __builtin_nontemporal_load(&sp[(size_t)c * S + s]);
    }
    __syncthreads();
    u16* dp = dst + (size_t)b * S * CCH + c0;
    #pragma unroll
    for (int i = 0; i < 16; ++i) {
        const int s = s0 + ty * 16 + i;
        if (s < S) dp[(size_t)s * CCH + tx] = f32_to_bf16(tile[tx][ty * 16 + i]);
    }
}

// Sort ROIs by (level, qy, qx) for L2 locality; key low bits = k (unique, deterministic)
__global__ __launch_bounds__(256) void roi_sort(
    const float* __restrict__ boxes, u32* __restrict__ perm)
{
    __shared__ u32 key[KTOT];
    for (int i = (int)threadIdx.x; i < KTOT; i += 256) {
        const float bx1 = boxes[4 * i + 0];
        const float by1 = boxes[4 * i + 1];
        const float bx2 = boxes[4 * i + 2];
        const float by2 = boxes[4 * i + 3];
        const float area = fmaxf((bx2 - bx1) * (by2 - by1), 0.0f);
        const float s    = sqrtf(area);
        float lvlf = floorf(4.0f + log2f(s / 224.0f) + 1e-6f);
        lvlf = fminf(fmaxf(lvlf, 2.0f), 5.0f);
        const u32 lvl = (u32)((int)lvlf - 2);
        const float cx = 0.5f * (bx1 + bx2);
        const float cy = 0.5f * (by1 + by2);
        const u32 qx = (u32)min(511, max(0, (int)(cx * 0.64f)));
        const u32 qy = (u32)min(511, max(0, (int)(cy * 0.64f)));
        key[i] = (lvl << 28) | (qy << 19) | (qx << 10) | (u32)i;
    }
    __syncthreads();
    for (int kk = 2; kk <= KTOT; kk <<= 1) {
        for (int j = kk >> 1; j > 0; j >>= 1) {
            for (int i = (int)threadIdx.x; i < KTOT; i += 256) {
                const int ixj = i ^ j;
                if (ixj > i) {
                    const u32 a = key[i], b = key[ixj];
                    const bool up = ((i & kk) == 0);
                    if ((a > b) == up) { key[i] = b; key[ixj] = a; }
                }
            }
            __syncthreads();
        }
    }
    for (int i = (int)threadIdx.x; i < KTOT; i += 256) perm[i] = key[i] & 1023u;
}

__device__ __forceinline__ void accum8(float* acc, float w, uint4 q) {
    acc[0] = fmaf(w, __uint_as_float(q.x << 16),          acc[0]);
    acc[1] = fmaf(w, __uint_as_float(q.x & 0xffff0000u),  acc[1]);
    acc[2] = fmaf(w, __uint_as_float(q.y << 16),          acc[2]);
    acc[3] = fmaf(w, __uint_as_float(q.y & 0xffff0000u),  acc[3]);
    acc[4] = fmaf(w, __uint_as_float(q.z << 16),          acc[4]);
    acc[5] = fmaf(w, __uint_as_float(q.z & 0xffff0000u),  acc[5]);
    acc[6] = fmaf(w, __uint_as_float(q.w << 16),          acc[6]);
    acc[7] = fmaf(w, __uint_as_float(q.w & 0xffff0000u),  acc[7]);
}

// One ROI per block. lane = (half, channel-octet); each half-wave handles one pixel
// per iteration (32 lanes x 16B = 512B = one full NHWC bf16 row of 256 channels).
// Output transposed to NCHW through an LDS tile -> coalesced final writes.
__global__ __launch_bounds__(256) void msroi_gather_bf16(
    const u16* __restrict__ g0, const u16* __restrict__ g1,
    const u16* __restrict__ g2, const u16* __restrict__ g3,
    const float* __restrict__ boxes, const u32* __restrict__ perm,
    float* __restrict__ out)
{
    __shared__ float tile[PIX * LDS_STRIDE];   // 51,156 B

    const int bid  = (int)blockIdx.x;
    const int sidx = ((bid & 7) << 7) | (bid >> 3);   // XCD gets contiguous sorted chunk
    const int k    = (int)perm[sidx];

    const int lane = (int)(threadIdx.x & 63u);
    const int wave = (int)(threadIdx.x >> 6);
    const int half = lane >> 5;
    const int c0   = (lane & 31) * 8;   // channel octet base

    // per-ROI params (wave-uniform)
    const float bx1 = boxes[4 * k + 0];
    const float by1 = boxes[4 * k + 1];
    const float bx2 = boxes[4 * k + 2];
    const float by2 = boxes[4 * k + 3];

    const float area = fmaxf((bx2 - bx1) * (by2 - by1), 0.0f);
    const float s    = sqrtf(area);
    float lvlf = floorf(4.0f + log2f(s / 224.0f) + 1e-6f);
    lvlf = fminf(fmaxf(lvlf, 2.0f), 5.0f);
    const int lvl = (int)lvlf - 2;

    const u16* g; int H, W; float scale;
    switch (lvl) {
        case 0:  g = g0; H = 200; W = 200; scale = 0.25f;    break;
        case 1:  g = g1; H = 100; W = 100; scale = 0.125f;   break;
        case 2:  g = g2; H =  50; W =  50; scale = 0.0625f;  break;
        default: g = g3; H =  25; W =  25; scale = 0.03125f; break;
    }

    const int b = k >> 9;
    const u16* __restrict__ fb = g + (size_t)b * (size_t)(H * W) * CCH;
    const int rowstride = W * CCH;

    const float rx1 = bx1 * scale, ry1 = by1 * scale;
    const float rx2 = bx2 * scale, ry2 = by2 * scale;
    const float bw = fmaxf(rx2 - rx1, 1.0f) / (float)OUTHW;
    const float bh = fmaxf(ry2 - ry1, 1.0f) / (float)OUTHW;
    const float Hf = (float)H, Wf = (float)W;

    #pragma unroll
    for (int i = 0; i < 7; ++i) {
        const int pp = 2 * i + half;            // 0..13 within wave's pixel set
        const int p  = wave * 13 + pp;
        const bool act = (pp < 13) && (p < PIX);
        const int pc = act ? p : (PIX - 1);
        const int ph = pc / OUTHW;
        const int pw = pc % OUTHW;

        float acc[8] = {0, 0, 0, 0, 0, 0, 0, 0};

        #pragma unroll
        for (int sy = 0; sy < 2; ++sy) {
            const float y  = ry1 + (float)ph * bh + ((float)sy + 0.5f) * bh / 2.0f;
            const bool  vy = (y >= -1.0f) && (y <= Hf);
            const float yc = fminf(fmaxf(y, 0.0f), Hf - 1.0f);
            int yl = (int)yc; if (yl > H - 2) yl = H - 2;
            const float ly = yc - (float)yl;

            #pragma unroll
            for (int sx = 0; sx < 2; ++sx) {
                const float x  = rx1 + (float)pw * bw + ((float)sx + 0.5f) * bw / 2.0f;
                const bool  vx = (x >= -1.0f) && (x <= Wf);
                const float xc = fminf(fmaxf(x, 0.0f), Wf - 1.0f);
                int xl = (int)xc; if (xl > W - 2) xl = W - 2;
                const float lx = xc - (float)xl;

                const float v   = (vy && vx) ? 1.0f : 0.0f;
                const float w00 = (1.0f - ly) * (1.0f - lx) * v;
                const float w01 = (1.0f - ly) * lx * v;
                const float w10 = ly * (1.0f - lx) * v;
                const float w11 = ly * lx * v;

                const u16* r0 = fb + (size_t)(yl * W + xl) * CCH + c0;
                const uint4 q00 = *reinterpret_cast<const uint4*>(r0);
                const uint4 q01 = *reinterpret_cast<const uint4*>(r0 + CCH);
                const uint4 q10 = *reinterpret_cast<const uint4*>(r0 + rowstride);
                const uint4 q11 = *reinterpret_cast<const uint4*>(r0 + rowstride + CCH);

                accum8(acc, w00, q00);
                accum8(acc, w01, q01);
                accum8(acc, w10, q10);
                accum8(acc, w11, q11);
            }
        }

        if (act) {
            float* tp = tile + pc * LDS_STRIDE + c0;
            #pragma unroll
            for (int j = 0; j < 8; ++j) tp[j] = acc[j] * 0.25f;
        }
    }

    __syncthreads();

    // NCHW output: flat = c*49 + p, fully coalesced (49*256 == CCH*PIX exactly)
    float* __restrict__ op = out + (size_t)k * (CCH * PIX);
    #pragma unroll
    for (int j = 0; j < PIX; ++j) {
        const int flat = j * 256 + (int)threadIdx.x;
        const int c = flat / PIX;
        const int p = flat % PIX;
        __builtin_nontemporal_store(tile[p * LDS_STRIDE + c], &op[flat]);
    }
}

// ===================== launch =====================
extern "C" void kernel_launch(void* const* d_in, const int* in_sizes, int n_in,
                              void* d_out, int out_size, void* d_ws, size_t ws_size,
                              hipStream_t stream) {
    const float* f0    = (const float*)d_in[0];
    const float* f1    = (const float*)d_in[1];
    const float* f2    = (const float*)d_in[2];
    const float* f3    = (const float*)d_in[3];
    const float* boxes = (const float*)d_in[4];
    float* out = (float*)d_out;

    const size_t n0 = 2ull * 200 * 200 * CCH;   // 20,480,000
    const size_t n1 = 2ull * 100 * 100 * CCH;   //  5,120,000
    const size_t n2 = 2ull *  50 *  50 * CCH;   //  1,280,000
    const size_t n3 = 2ull *  25 *  25 * CCH;   //    320,000
    const size_t need = (n0 + n1 + n2 + n3) * sizeof(u16) + KTOT * sizeof(u32);

    if (ws_size >= need) {
        u16* g0 = (u16*)d_ws;
        u16* g1 = g0 + n0;
        u16* g2 = g1 + n1;
        u16* g3 = g2 + n2;
        u32* perm = (u32*)(g3 + n3);

        roi_sort<<<1, 256, 0, stream>>>(boxes, perm);

        nchw_to_nhwc_bf16<<<dim3(625, 4, 2), 256, 0, stream>>>(f0, g0, 40000);
        nchw_to_nhwc_bf16<<<dim3(157, 4, 2), 256, 0, stream>>>(f1, g1, 10000);
        nchw_to_nhwc_bf16<<<dim3( 40, 4, 2), 256, 0, stream>>>(f2, g2,  2500);
        nchw_to_nhwc_bf16<<<dim3( 10, 4, 2), 256, 0, stream>>>(f3, g3,   625);

        msroi_gather_bf16<<<dim3(KTOT), 256, 0, stream>>>(g0, g1, g2, g3, boxes, perm, out);
    } else {
        const int total = KTOT * CCH * PIX;
        msroi_fallback<<<(total + 255) / 256, 256, 0, stream>>>(f0, f1, f2, f3, boxes, out);
    }
}